// Round 4
// baseline (265.304 us; speedup 1.0000x reference)
//
#include <hip/hip_runtime.h>
#include <cstdint>
#include <cstddef>

typedef short bf16x8 __attribute__((ext_vector_type(8)));
typedef float f32x4 __attribute__((ext_vector_type(4)));

#define EPS 1e-3f

__device__ __forceinline__ short f32_to_bf16s(float f) {
    union { float f; uint32_t u; } v; v.f = f;
    return (short)((v.u + 0x7FFFu + ((v.u >> 16) & 1u)) >> 16);
}

// K0: wt[kp][ci] = bf16(W[ci][kp]) (192x64); at[w][k] = bf16(A[p][v][w]) (32x96, k=p*25+v, zero-padded)
__global__ __launch_bounds__(256) void prep_kernel(const float* __restrict__ A,
                                                   const float* __restrict__ W,
                                                   unsigned short* __restrict__ wt,
                                                   unsigned short* __restrict__ at) {
    int idx = blockIdx.x * 256 + threadIdx.x;
    if (idx < 12288) {
        int kp = idx >> 6, ci = idx & 63;
        wt[idx] = (unsigned short)f32_to_bf16s(W[ci * 192 + kp]);
    } else {
        int j = idx - 12288;
        if (j < 3072) {
            int w = j / 96, k = j - w * 96;
            float val = 0.f;
            if (w < 25 && k < 75) {
                int p = k / 25, v = k - p * 25;
                val = A[(p * 25 + v) * 25 + w];
            }
            at[j] = (unsigned short)f32_to_bf16s(val);
        }
    }
}

// ---- phase-1 split helpers (issue 16 loads / consume window+LDS-write).
// v1-style predicated ternary loads (exec-masked); only 16 floats live between the two.
__device__ __forceinline__ void p1_issue(const float* __restrict__ xn, int l0, int cidx,
                                         float* v16) {
    bool act = cidx < 1600;
    int cc = act ? cidx : 0;
    int ci = cc / 25, v = cc - ci * 25;
    const float* xp = xn + (size_t)ci * 7500 + v;
    #pragma unroll
    for (int i = 0; i < 16; ++i) {
        int l = l0 - 8 + i;
        v16[i] = (act && l >= 0 && l < 300) ? xp[l * 25] : 0.f;
    }
}

__device__ __forceinline__ void p1_consume(short* __restrict__ xbuf, int cidx,
                                           const float* v16) {
    if (cidx < 1600) {
        int ci = cidx / 25, v = cidx - ci * 25;
        float run = v16[0] + v16[1] + v16[2] + v16[3]
                  + v16[4] + v16[5] + v16[6] + v16[7];
        short* wb = &xbuf[(ci >> 3) * 1656 + (ci & 7)];
        #pragma unroll
        for (int j = 0; j < 8; ++j) {
            run += v16[j + 8];
            wb[(j * 25 + v) * 8] = f32_to_bf16s(run);
            run -= v16[j];
        }
    }
}

// ---- one output c-group: GEMM1 (W^T x xw), stage to Ys slab, GEMM2 (x A), BN+res epilogue
// (identical to v1's do_group; region0 = smem base)
__device__ __forceinline__ void do_group(int g, const unsigned short* __restrict__ wt,
    short* smem, const bf16x8 (&b1)[2][2], const bf16x8 (&b2)[2][3],
    const float* __restrict__ xn, float* __restrict__ outn,
    const float* scs, const float* shs,
    int lg, int wv, int q, int lcol)
{
    bf16x8 a1[3][2];
    #pragma unroll
    for (int mt = 0; mt < 3; ++mt)
        #pragma unroll
        for (int s = 0; s < 2; ++s)
            a1[mt][s] = *(const bf16x8*)(wt + (size_t)(g * 48 + mt * 16 + lcol) * 64 + 32 * s + 8 * q);

    f32x4 acc[3][2];
    #pragma unroll
    for (int mt = 0; mt < 3; ++mt)
        #pragma unroll
        for (int nt = 0; nt < 2; ++nt) acc[mt][nt] = (f32x4){0.f, 0.f, 0.f, 0.f};
    #pragma unroll
    for (int s = 0; s < 2; ++s)
        #pragma unroll
        for (int mt = 0; mt < 3; ++mt) {
            bf16x8 av = a1[mt][s];
            #pragma unroll
            for (int nt = 0; nt < 2; ++nt)
                acc[mt][nt] = __builtin_amdgcn_mfma_f32_16x16x32_bf16(av, b1[nt][s], acc[mt][nt], 0, 0, 0);
        }

    // residual prefetch (L2-hot: rows fetched by this block's phase-1)
    const size_t rbase = (size_t)lg * 25;
    float res[2][4];
    #pragma unroll
    for (int nt = 0; nt < 2; ++nt) {
        int w = nt * 16 + lcol;
        bool val = (w < 25) && (lg < 300);
        #pragma unroll
        for (int r = 0; r < 4; ++r) {
            int c = g * 16 + 4 * q + r;
            res[nt][r] = val ? xn[rbase + (size_t)c * 7500 + w] : 0.f;
        }
    }

    // stage D -> own Ys slab (wave-private, no barrier; compiler orders via lgkmcnt)
    #pragma unroll
    for (int mt = 0; mt < 3; ++mt)
        #pragma unroll
        for (int nt = 0; nt < 2; ++nt) {
            int v = nt * 16 + lcol;
            if (v < 25) {
                #pragma unroll
                for (int r = 0; r < 4; ++r) {
                    int kpl = mt * 16 + 4 * q + r;
                    int cl = kpl / 3, p = kpl - 3 * cl;
                    smem[(wv * 16 + cl) * 104 + 25 * p + v] = f32_to_bf16s(acc[mt][nt][r]);
                }
            }
        }

    f32x4 c0 = {0.f, 0.f, 0.f, 0.f}, c1 = {0.f, 0.f, 0.f, 0.f};
    #pragma unroll
    for (int s = 0; s < 3; ++s) {
        bf16x8 a2 = *(const bf16x8*)&smem[(wv * 16 + lcol) * 104 + 32 * s + 8 * q];
        c0 = __builtin_amdgcn_mfma_f32_16x16x32_bf16(a2, b2[0][s], c0, 0, 0, 0);
        c1 = __builtin_amdgcn_mfma_f32_16x16x32_bf16(a2, b2[1][s], c1, 0, 0, 0);
    }

    if (lg < 300) {
        #pragma unroll
        for (int nt = 0; nt < 2; ++nt) {
            int w = nt * 16 + lcol;
            if (w < 25) {
                f32x4 cc = nt ? c1 : c0;
                #pragma unroll
                for (int r = 0; r < 4; ++r) {
                    int c = g * 16 + 4 * q + r;
                    float o = fmaxf(cc[r] * scs[c] + shs[c], 0.f);
                    outn[rbase + (size_t)c * 7500 + w] = fmaxf(o + res[nt][r], 0.f);
                }
            }
        }
    }
}

// Mega v5: n-pair per block, LDS double-buffered cross-sample pipeline.
// region0 = smem[0..13312) : xwL(n0) -> Ys (aliased, v1 layout)
// X1      = smem[13312..26560) : xwL(n1), filled DURING n0's GEMM phase.
// n1's phase-1 reps interleave with n0's do_groups: issue 16 loads before group g,
// consume+write X1 after it (only 16 floats live across one group -> no spill;
// VGPR cap is 85 at 6 waves/EU). LDS 53,632 B -> 3 blocks/CU; grid 608 <= 768
// slots -> zero dispatch tail. Barriers: 3 per 2 samples (was 4).
__global__ __launch_bounds__(512, 6) void mega_kernel(
    const float* __restrict__ x,
    const unsigned short* __restrict__ wt,
    const unsigned short* __restrict__ at,
    const float* __restrict__ gamma, const float* __restrict__ beta,
    const float* __restrict__ mean, const float* __restrict__ var,
    float* __restrict__ out) {
    const int ch = blockIdx.x;
    const int n0 = blockIdx.y * 2;
    const int l0 = ch * 8;
    const int tid = threadIdx.x;
    const int wv = tid >> 6, lane = tid & 63, q = lane >> 4, lcol = lane & 15;

    __shared__ __align__(16) short smem[26560];
    __shared__ float scs[64], shs[64];
    short* X1 = smem + 13312;

    const float* xn0 = x + (size_t)n0 * 480000;
    const float* xn1 = xn0 + 480000;
    float* outn0 = out + (size_t)n0 * 480000;
    float* outn1 = outn0 + 480000;

    // b2 fragments (at, L2-resident) + BN constants — issued before phase-1 (overlap)
    bf16x8 b2[2][3];
    #pragma unroll
    for (int nt = 0; nt < 2; ++nt)
        #pragma unroll
        for (int s = 0; s < 3; ++s)
            b2[nt][s] = *(const bf16x8*)(at + (size_t)(nt * 16 + lcol) * 96 + 32 * s + 8 * q);
    if (tid < 64) {
        float sc = gamma[tid] * rsqrtf(var[tid] + EPS);
        scs[tid] = sc;
        shs[tid] = beta[tid] - mean[tid] * sc;
    }

    // Phase 1 for n0 (v1 verbatim: batched 16-load reps, unroll 1) -> region0
    #pragma unroll 1
    for (int rep = 0; rep < 4; ++rep) {
        int cidx = tid + rep * 512;
        float t16[16];
        p1_issue(xn0, l0, cidx, t16);
        p1_consume(smem, cidx, t16);
    }
    __syncthreads();   // B1: xwL(n0) ready

    // b1(n0) fragments (cols >= 200 are stale-but-finite garbage; their D-columns
    // map to v>=25 and are never stored — harmless even if NaN, per-column MFMA)
    bf16x8 b1[2][2];
    #pragma unroll
    for (int nt = 0; nt < 2; ++nt) {
        int col = wv * 25 + nt * 16 + lcol;
        #pragma unroll
        for (int s = 0; s < 2; ++s)
            b1[nt][s] = *(const bf16x8*)&smem[(4 * s + q) * 1656 + col * 8];
    }
    __syncthreads();   // B2: xwL(n0) reads done; region0 becomes Ys

    // Zero own Ys slab pad cols [72,104) — stays zero across both samples
    #pragma unroll
    for (int i = lane; i < 512; i += 64) {
        int r = i >> 5, cc = 72 + (i & 31);
        smem[(wv * 16 + r) * 104 + cc] = 0;
    }

    const int lg = l0 + wv;

    // n0 GEMM groups with n1 phase-1 reps pipelined into X1 (loads before group,
    // consume after -> HBM latency hides under MFMA/LDS work of the group)
    {
        float v16[16];
        p1_issue(xn1, l0, tid, v16);
        do_group(0, wt, smem, b1, b2, xn0, outn0, scs, shs, lg, wv, q, lcol);
        p1_consume(X1, tid, v16);

        p1_issue(xn1, l0, tid + 512, v16);
        do_group(1, wt, smem, b1, b2, xn0, outn0, scs, shs, lg, wv, q, lcol);
        p1_consume(X1, tid + 512, v16);

        p1_issue(xn1, l0, tid + 1024, v16);
        do_group(2, wt, smem, b1, b2, xn0, outn0, scs, shs, lg, wv, q, lcol);
        p1_consume(X1, tid + 1024, v16);

        p1_issue(xn1, l0, tid + 1536, v16);
        do_group(3, wt, smem, b1, b2, xn0, outn0, scs, shs, lg, wv, q, lcol);
        p1_consume(X1, tid + 1536, v16);
    }
    __syncthreads();   // B3: xwL(n1) ready (Ys slabs are wave-private: no extra barrier)

    // b1(n1) from X1; subsequent Ys(n1) writes go to region0 — disjoint from X1,
    // and own slab reads of n0 finished in program order -> no barrier needed after.
    #pragma unroll
    for (int nt = 0; nt < 2; ++nt) {
        int col = wv * 25 + nt * 16 + lcol;
        #pragma unroll
        for (int s = 0; s < 2; ++s)
            b1[nt][s] = *(const bf16x8*)&X1[(4 * s + q) * 1656 + col * 8];
    }

    #pragma unroll 1
    for (int g = 0; g < 4; ++g)
        do_group(g, wt, smem, b1, b2, xn1, outn1, scs, shs, lg, wv, q, lcol);
}

extern "C" void kernel_launch(void* const* d_in, const int* in_sizes, int n_in,
                              void* d_out, int out_size, void* d_ws, size_t ws_size,
                              hipStream_t stream) {
    const float* x     = (const float*)d_in[0];
    const float* A     = (const float*)d_in[1];
    const float* W     = (const float*)d_in[2];
    const float* gamma = (const float*)d_in[3];
    const float* beta  = (const float*)d_in[4];
    const float* mean  = (const float*)d_in[5];
    const float* var   = (const float*)d_in[6];
    float* out = (float*)d_out;

    char* ws = (char*)d_ws;
    unsigned short* wt = (unsigned short*)ws;               // 24,576 B
    unsigned short* at = (unsigned short*)(ws + 24576);     // 6,144 B

    prep_kernel<<<60, 256, 0, stream>>>(A, W, wt, at);
    mega_kernel<<<dim3(38, 16), 512, 0, stream>>>(x, wt, at, gamma, beta, mean, var, out);
}

// Round 5
// 175.880 us; speedup vs baseline: 1.5084x; 1.5084x over previous
//
#include <hip/hip_runtime.h>
#include <cstdint>
#include <cstddef>

typedef short bf16x8 __attribute__((ext_vector_type(8)));
typedef float f32x4 __attribute__((ext_vector_type(4)));

#define EPS 1e-3f

__device__ __forceinline__ short f32_to_bf16s(float f) {
    union { float f; uint32_t u; } v; v.f = f;
    return (short)((v.u + 0x7FFFu + ((v.u >> 16) & 1u)) >> 16);
}

// K0: wt[kp][ci] = bf16(W[ci][kp]) (192x64); at[w][k] = bf16(A[p][v][w]) (32x96, k=p*25+v, zero-padded)
__global__ __launch_bounds__(256) void prep_kernel(const float* __restrict__ A,
                                                   const float* __restrict__ W,
                                                   unsigned short* __restrict__ wt,
                                                   unsigned short* __restrict__ at) {
    int idx = blockIdx.x * 256 + threadIdx.x;
    if (idx < 12288) {
        int kp = idx >> 6, ci = idx & 63;
        wt[idx] = (unsigned short)f32_to_bf16s(W[ci * 192 + kp]);
    } else {
        int j = idx - 12288;
        if (j < 3072) {
            int w = j / 96, k = j - w * 96;
            float val = 0.f;
            if (w < 25 && k < 75) {
                int p = k / 25, v = k - p * 25;
                val = A[(p * 25 + v) * 25 + w];
            }
            at[j] = (unsigned short)f32_to_bf16s(val);
        }
    }
}

// ---- phase-1 split helpers (issue 16 loads / consume window+LDS-write).
__device__ __forceinline__ void p1_issue(const float* __restrict__ xn, int l0, int cidx,
                                         float* v16) {
    bool act = cidx < 1600;
    int cc = act ? cidx : 0;
    int ci = cc / 25, v = cc - ci * 25;
    const float* xp = xn + (size_t)ci * 7500 + v;
    #pragma unroll
    for (int i = 0; i < 16; ++i) {
        int l = l0 - 8 + i;
        v16[i] = (act && l >= 0 && l < 300) ? xp[l * 25] : 0.f;
    }
}

__device__ __forceinline__ void p1_consume(short* __restrict__ xbuf, int cidx,
                                           const float* v16) {
    if (cidx < 1600) {
        int ci = cidx / 25, v = cidx - ci * 25;
        float run = v16[0] + v16[1] + v16[2] + v16[3]
                  + v16[4] + v16[5] + v16[6] + v16[7];
        short* wb = &xbuf[(ci >> 3) * 1656 + (ci & 7)];
        #pragma unroll
        for (int j = 0; j < 8; ++j) {
            run += v16[j + 8];
            wb[(j * 25 + v) * 8] = f32_to_bf16s(run);
            run -= v16[j];
        }
    }
}

// ---- one output c-group: GEMM1 (W^T x xw), stage to Ys slab, GEMM2 (x A), BN+res epilogue
// (v1 verbatim; smem = Ys region base)
__device__ __forceinline__ void do_group(int g, const unsigned short* __restrict__ wt,
    short* smem, const bf16x8 (&b1)[2][2], const bf16x8 (&b2)[2][3],
    const float* __restrict__ xn, float* __restrict__ outn,
    const float* scs, const float* shs,
    int lg, int wv, int q, int lcol)
{
    bf16x8 a1[3][2];
    #pragma unroll
    for (int mt = 0; mt < 3; ++mt)
        #pragma unroll
        for (int s = 0; s < 2; ++s)
            a1[mt][s] = *(const bf16x8*)(wt + (size_t)(g * 48 + mt * 16 + lcol) * 64 + 32 * s + 8 * q);

    f32x4 acc[3][2];
    #pragma unroll
    for (int mt = 0; mt < 3; ++mt)
        #pragma unroll
        for (int nt = 0; nt < 2; ++nt) acc[mt][nt] = (f32x4){0.f, 0.f, 0.f, 0.f};
    #pragma unroll
    for (int s = 0; s < 2; ++s)
        #pragma unroll
        for (int mt = 0; mt < 3; ++mt) {
            bf16x8 av = a1[mt][s];
            #pragma unroll
            for (int nt = 0; nt < 2; ++nt)
                acc[mt][nt] = __builtin_amdgcn_mfma_f32_16x16x32_bf16(av, b1[nt][s], acc[mt][nt], 0, 0, 0);
        }

    // residual prefetch (L1/L2-hot: rows read by this block's phase-1)
    const size_t rbase = (size_t)lg * 25;
    float res[2][4];
    #pragma unroll
    for (int nt = 0; nt < 2; ++nt) {
        int w = nt * 16 + lcol;
        bool val = (w < 25) && (lg < 300);
        #pragma unroll
        for (int r = 0; r < 4; ++r) {
            int c = g * 16 + 4 * q + r;
            res[nt][r] = val ? xn[rbase + (size_t)c * 7500 + w] : 0.f;
        }
    }

    // stage D -> own Ys slab (wave-private, no barrier; compiler orders via lgkmcnt)
    #pragma unroll
    for (int mt = 0; mt < 3; ++mt)
        #pragma unroll
        for (int nt = 0; nt < 2; ++nt) {
            int v = nt * 16 + lcol;
            if (v < 25) {
                #pragma unroll
                for (int r = 0; r < 4; ++r) {
                    int kpl = mt * 16 + 4 * q + r;
                    int cl = kpl / 3, p = kpl - 3 * cl;
                    smem[(wv * 16 + cl) * 104 + 25 * p + v] = f32_to_bf16s(acc[mt][nt][r]);
                }
            }
        }

    f32x4 c0 = {0.f, 0.f, 0.f, 0.f}, c1 = {0.f, 0.f, 0.f, 0.f};
    #pragma unroll
    for (int s = 0; s < 3; ++s) {
        bf16x8 a2 = *(const bf16x8*)&smem[(wv * 16 + lcol) * 104 + 32 * s + 8 * q];
        c0 = __builtin_amdgcn_mfma_f32_16x16x32_bf16(a2, b2[0][s], c0, 0, 0, 0);
        c1 = __builtin_amdgcn_mfma_f32_16x16x32_bf16(a2, b2[1][s], c1, 0, 0, 0);
    }

    if (lg < 300) {
        #pragma unroll
        for (int nt = 0; nt < 2; ++nt) {
            int w = nt * 16 + lcol;
            if (w < 25) {
                f32x4 cc = nt ? c1 : c0;
                #pragma unroll
                for (int r = 0; r < 4; ++r) {
                    int c = g * 16 + 4 * q + r;
                    float o = fmaxf(cc[r] * scs[c] + shs[c], 0.f);
                    outn[rbase + (size_t)c * 7500 + w] = fmaxf(o + res[nt][r], 0.f);
                }
            }
        }
    }
}

// Mega v6: block = (ch-PAIR, n), grid 19x32=608. Chunk1 (l0+8) phase-1 pipelines
// under chunk0's GEMM via LDS X1 buffer; chunk1's loads re-hit chunk0's halo rows
// in L1/L2 (same n, adjacent l) -> FETCH drops, latency hidden.
// LDS: X0 [0,13312) = xwL(chunk0) aliased-> Ys; X1 [13312,26560) = xwL(chunk1).
// 53,632 B -> 3 blocks/CU (24 waves, 6/EU) iff VGPR<=85:
// amdgpu_waves_per_eu(4,6) budgets for 6 waves/EU (cap ~85) so the backend
// neither squeezes to 64-and-spills (v2) nor is strangled to 85-with-bigger-set (v5).
__global__ __launch_bounds__(512) __attribute__((amdgpu_waves_per_eu(4, 6)))
void mega_kernel(
    const float* __restrict__ x,
    const unsigned short* __restrict__ wt,
    const unsigned short* __restrict__ at,
    const float* __restrict__ gamma, const float* __restrict__ beta,
    const float* __restrict__ mean, const float* __restrict__ var,
    float* __restrict__ out) {
    const int l0 = blockIdx.x * 16;       // chunk0: l0..l0+7, chunk1: l0+8..l0+15
    const int n  = blockIdx.y;
    const int tid = threadIdx.x;
    const int wv = tid >> 6, lane = tid & 63, q = lane >> 4, lcol = lane & 15;

    __shared__ __align__(16) short smem[26560];
    __shared__ float scs[64], shs[64];
    short* X1 = smem + 13312;

    const float* xn  = x   + (size_t)n * 480000;
    float*       outn = out + (size_t)n * 480000;

    // b2 fragments (at, L2-resident) + BN constants
    bf16x8 b2[2][3];
    #pragma unroll
    for (int nt = 0; nt < 2; ++nt)
        #pragma unroll
        for (int s = 0; s < 3; ++s)
            b2[nt][s] = *(const bf16x8*)(at + (size_t)(nt * 16 + lcol) * 96 + 32 * s + 8 * q);
    if (tid < 64) {
        float sc = gamma[tid] * rsqrtf(var[tid] + EPS);
        scs[tid] = sc;
        shs[tid] = beta[tid] - mean[tid] * sc;
    }

    // Phase 1 chunk0 -> X0 (v1-style batched reps)
    #pragma unroll 1
    for (int rep = 0; rep < 4; ++rep) {
        int cidx = tid + rep * 512;
        float t16[16];
        p1_issue(xn, l0, cidx, t16);
        p1_consume(smem, cidx, t16);
    }
    __syncthreads();   // B1: xwL(chunk0) ready

    // b1(chunk0) fragments (cols>=200: stale-but-finite, D-cols map to w>=25, never stored)
    bf16x8 b1[2][2];
    #pragma unroll
    for (int nt = 0; nt < 2; ++nt) {
        int col = wv * 25 + nt * 16 + lcol;
        #pragma unroll
        for (int s = 0; s < 2; ++s)
            b1[nt][s] = *(const bf16x8*)&smem[(4 * s + q) * 1656 + col * 8];
    }
    __syncthreads();   // B2: X0 reads done; X0 region becomes Ys

    // Zero own Ys slab pad cols [72,104): stays valid across both chunks
    // (staging rewrites cols 0..74 every group; 75..95 remain zero)
    #pragma unroll
    for (int i = lane; i < 512; i += 64) {
        int r = i >> 5, cc = 72 + (i & 31);
        smem[(wv * 16 + r) * 104 + cc] = 0;
    }

    const int lg0 = l0 + wv;
    const int l1  = l0 + 8;

    // chunk0 GEMM groups with chunk1 phase-1 pipelined into X1.
    // sched_barrier(0) pins the loads above the group (anti-sinking, v4 lesson).
    {
        float v16[16];
        p1_issue(xn, l1, tid, v16);
        __builtin_amdgcn_sched_barrier(0);
        do_group(0, wt, smem, b1, b2, xn, outn, scs, shs, lg0, wv, q, lcol);
        p1_consume(X1, tid, v16);

        p1_issue(xn, l1, tid + 512, v16);
        __builtin_amdgcn_sched_barrier(0);
        do_group(1, wt, smem, b1, b2, xn, outn, scs, shs, lg0, wv, q, lcol);
        p1_consume(X1, tid + 512, v16);

        p1_issue(xn, l1, tid + 1024, v16);
        __builtin_amdgcn_sched_barrier(0);
        do_group(2, wt, smem, b1, b2, xn, outn, scs, shs, lg0, wv, q, lcol);
        p1_consume(X1, tid + 1024, v16);

        p1_issue(xn, l1, tid + 1536, v16);
        __builtin_amdgcn_sched_barrier(0);
        do_group(3, wt, smem, b1, b2, xn, outn, scs, shs, lg0, wv, q, lcol);
        p1_consume(X1, tid + 1536, v16);
    }
    __syncthreads();   // B3: xwL(chunk1) complete (Ys slabs are wave-private)

    // b1(chunk1) from X1; Ys writes go to X0 region (disjoint from X1) -> no barrier
    #pragma unroll
    for (int nt = 0; nt < 2; ++nt) {
        int col = wv * 25 + nt * 16 + lcol;
        #pragma unroll
        for (int s = 0; s < 2; ++s)
            b1[nt][s] = *(const bf16x8*)&X1[(4 * s + q) * 1656 + col * 8];
    }

    const int lg1 = l1 + wv;
    #pragma unroll 1
    for (int g = 0; g < 4; ++g)
        do_group(g, wt, smem, b1, b2, xn, outn, scs, shs, lg1, wv, q, lcol);
}

extern "C" void kernel_launch(void* const* d_in, const int* in_sizes, int n_in,
                              void* d_out, int out_size, void* d_ws, size_t ws_size,
                              hipStream_t stream) {
    const float* x     = (const float*)d_in[0];
    const float* A     = (const float*)d_in[1];
    const float* W     = (const float*)d_in[2];
    const float* gamma = (const float*)d_in[3];
    const float* beta  = (const float*)d_in[4];
    const float* mean  = (const float*)d_in[5];
    const float* var   = (const float*)d_in[6];
    float* out = (float*)d_out;

    char* ws = (char*)d_ws;
    unsigned short* wt = (unsigned short*)ws;               // 24,576 B
    unsigned short* at = (unsigned short*)(ws + 24576);     // 6,144 B

    prep_kernel<<<60, 256, 0, stream>>>(A, W, wt, at);
    mega_kernel<<<dim3(19, 32), 512, 0, stream>>>(x, wt, at, gamma, beta, mean, var, out);
}

// Round 6
// 162.240 us; speedup vs baseline: 1.6353x; 1.0841x over previous
//
#include <hip/hip_runtime.h>
#include <cstdint>
#include <cstddef>

typedef short bf16x8 __attribute__((ext_vector_type(8)));
typedef float f32x4 __attribute__((ext_vector_type(4)));

#define EPS 1e-3f

__device__ __forceinline__ short f32_to_bf16s(float f) {
    union { float f; uint32_t u; } v; v.f = f;
    return (short)((v.u + 0x7FFFu + ((v.u >> 16) & 1u)) >> 16);
}

// K0: wt[kp][ci] = bf16(W[ci][kp]) (192x64); at[w][k] = bf16(A[p][v][w]) (32x96, k=p*25+v, zero-padded)
__global__ __launch_bounds__(256) void prep_kernel(const float* __restrict__ A,
                                                   const float* __restrict__ W,
                                                   unsigned short* __restrict__ wt,
                                                   unsigned short* __restrict__ at) {
    int idx = blockIdx.x * 256 + threadIdx.x;
    if (idx < 12288) {
        int kp = idx >> 6, ci = idx & 63;
        wt[idx] = (unsigned short)f32_to_bf16s(W[ci * 192 + kp]);
    } else {
        int j = idx - 12288;
        if (j < 3072) {
            int w = j / 96, k = j - w * 96;
            float val = 0.f;
            if (w < 25 && k < 75) {
                int p = k / 25, v = k - p * 25;
                val = A[(p * 25 + v) * 25 + w];
            }
            at[j] = (unsigned short)f32_to_bf16s(val);
        }
    }
}

// Mega v7 = v1 (the 73.6 us best: 1 sample/block, 27.1 KB LDS, 4 blocks/CU = 32
// waves/CU, batched phase-1) + XCD-chunked blockIdx swizzle ONLY.
// Session lesson: every restructure that cut resident waves below 32/CU lost
// (v3 19w=88us, v6 24w=83.5us); the only clean traffic win was the swizzle
// (v4: FETCH 92->44 MB) but it was never isolated on v1's structure. One variable.
__global__ __launch_bounds__(512, 4) void mega_kernel(
    const float* __restrict__ x,
    const unsigned short* __restrict__ wt,
    const unsigned short* __restrict__ at,
    const float* __restrict__ gamma, const float* __restrict__ beta,
    const float* __restrict__ mean, const float* __restrict__ var,
    float* __restrict__ out) {
    // XCD-chunked swizzle: HW round-robins lin over 8 XCDs; bijective (1216 = 8*152).
    // XCD k owns logical [152k,152k+152) = n in [4k,4k+4), all ch, consecutive ch
    // adjacent in time -> halo lines + residual rows L2-hot within the XCD.
    const int lin = blockIdx.x + 38 * blockIdx.y;        // 0..1215
    const int logical = (lin & 7) * 152 + (lin >> 3);
    const int ch = logical % 38;
    const int n  = logical / 38;

    const int l0 = ch * 8;
    const int tid = threadIdx.x;
    const int wv = tid >> 6, lane = tid & 63, q = lane >> 4, lcol = lane & 15;

    __shared__ __align__(16) short smem[13312];   // xwL (13248) then Ys (13312)
    __shared__ float scs[64], shs[64];

    // b2 fragments (at, L2-resident) + BN constants — prefetched before phase 1
    bf16x8 b2[2][3];
    #pragma unroll
    for (int nt = 0; nt < 2; ++nt)
        #pragma unroll
        for (int s = 0; s < 3; ++s)
            b2[nt][s] = *(const bf16x8*)(at + (size_t)(nt * 16 + lcol) * 96 + 32 * s + 8 * q);
    if (tid < 64) {
        float sc = gamma[tid] * rsqrtf(var[tid] + EPS);
        scs[tid] = sc;
        shs[tid] = beta[tid] - mean[tid] * sc;
    }

    // Phase 1: per-(ci,v) running 9-window over l = l0..l0+7 -> xwL (bf16)
    #pragma unroll 1
    for (int rep = 0; rep < 4; ++rep) {
        int cidx = tid + rep * 512;
        if (cidx < 1600) {
            int ci = cidx / 25, v = cidx - ci * 25;
            const float* xp = x + (size_t)(n * 64 + ci) * 7500 + v;
            float vals[16];
            #pragma unroll
            for (int i = 0; i < 16; ++i) {
                int l = l0 - 8 + i;
                vals[i] = (l >= 0 && l < 300) ? xp[l * 25] : 0.f;
            }
            float run = vals[0] + vals[1] + vals[2] + vals[3]
                      + vals[4] + vals[5] + vals[6] + vals[7];
            short* wb = &smem[(ci >> 3) * 1656 + (ci & 7)];
            #pragma unroll
            for (int j = 0; j < 8; ++j) {
                run += vals[j + 8];
                wb[(j * 25 + v) * 8] = f32_to_bf16s(run);
                run -= vals[j];
            }
        }
    }
    __syncthreads();   // barrier 1: xwL ready

    // b1 fragments: B[k=ci][col], cols wv*25 + nt*16 + lcol (<=206; cols>=200 are
    // stale-but-finite garbage whose D-columns map to w>=25 and are never stored)
    bf16x8 b1[2][2];
    #pragma unroll
    for (int nt = 0; nt < 2; ++nt) {
        int col = wv * 25 + nt * 16 + lcol;
        #pragma unroll
        for (int s = 0; s < 2; ++s)
            b1[nt][s] = *(const bf16x8*)&smem[(4 * s + q) * 1656 + col * 8];
    }
    __syncthreads();   // barrier 2: all xwL reads done; smem becomes Ys

    // Zero own Ys slab pad cols [72,104): wave-private from here on.
    #pragma unroll
    for (int i = lane; i < 512; i += 64) {
        int r = i >> 5, cc = 72 + (i & 31);
        smem[(wv * 16 + r) * 104 + cc] = 0;
    }

    const int lg = l0 + wv;
    const size_t outrow = ((size_t)n * 64 * 300 + lg) * 25;   // + c*7500 + w

    #pragma unroll 1
    for (int g = 0; g < 4; ++g) {
        // a1 fragments for this c-group (wt, L1/L2-resident)
        bf16x8 a1[3][2];
        #pragma unroll
        for (int mt = 0; mt < 3; ++mt)
            #pragma unroll
            for (int s = 0; s < 2; ++s)
                a1[mt][s] = *(const bf16x8*)(wt + (size_t)(g * 48 + mt * 16 + lcol) * 64 + 32 * s + 8 * q);

        // GEMM1: M=48 (kp of group g), N=32 (own l, v+pad), K=64
        f32x4 acc[3][2];
        #pragma unroll
        for (int mt = 0; mt < 3; ++mt)
            #pragma unroll
            for (int nt = 0; nt < 2; ++nt) acc[mt][nt] = (f32x4){0.f, 0.f, 0.f, 0.f};
        #pragma unroll
        for (int s = 0; s < 2; ++s)
            #pragma unroll
            for (int mt = 0; mt < 3; ++mt) {
                bf16x8 av = a1[mt][s];
                #pragma unroll
                for (int nt = 0; nt < 2; ++nt)
                    acc[mt][nt] = __builtin_amdgcn_mfma_f32_16x16x32_bf16(av, b1[nt][s], acc[mt][nt], 0, 0, 0);
            }

        // Residual prefetch (L2-hot: same rows fetched by phase 1 of this block)
        float res[2][4];
        #pragma unroll
        for (int nt = 0; nt < 2; ++nt) {
            int w = nt * 16 + lcol;
            bool val = (w < 25) && (lg < 300);
            #pragma unroll
            for (int r = 0; r < 4; ++r) {
                int c = g * 16 + 4 * q + r;
                res[nt][r] = val ? x[outrow + (size_t)c * 7500 + w] : 0.f;
            }
        }

        // Stage D -> own Ys slab rows (wv*16+cl), col 25p+v   (wave-private, no barrier)
        #pragma unroll
        for (int mt = 0; mt < 3; ++mt)
            #pragma unroll
            for (int nt = 0; nt < 2; ++nt) {
                int v = nt * 16 + lcol;
                if (v < 25) {
                    #pragma unroll
                    for (int r = 0; r < 4; ++r) {
                        int kpl = mt * 16 + 4 * q + r;
                        int cl = kpl / 3, p = kpl - 3 * cl;
                        smem[(wv * 16 + cl) * 104 + 25 * p + v] = f32_to_bf16s(acc[mt][nt][r]);
                    }
                }
            }

        // GEMM2: M=16 (cl), N=32 (w), K=96 — reads own slab (compiler orders via lgkmcnt)
        f32x4 c0 = {0.f, 0.f, 0.f, 0.f}, c1 = {0.f, 0.f, 0.f, 0.f};
        #pragma unroll
        for (int s = 0; s < 3; ++s) {
            bf16x8 a2 = *(const bf16x8*)&smem[(wv * 16 + lcol) * 104 + 32 * s + 8 * q];
            c0 = __builtin_amdgcn_mfma_f32_16x16x32_bf16(a2, b2[0][s], c0, 0, 0, 0);
            c1 = __builtin_amdgcn_mfma_f32_16x16x32_bf16(a2, b2[1][s], c1, 0, 0, 0);
        }

        // Epilogue: BN + ReLU + residual + ReLU
        if (lg < 300) {
            #pragma unroll
            for (int nt = 0; nt < 2; ++nt) {
                int w = nt * 16 + lcol;
                if (w < 25) {
                    f32x4 cc = nt ? c1 : c0;
                    #pragma unroll
                    for (int r = 0; r < 4; ++r) {
                        int c = g * 16 + 4 * q + r;
                        float o = fmaxf(cc[r] * scs[c] + shs[c], 0.f);
                        out[outrow + (size_t)c * 7500 + w] = fmaxf(o + res[nt][r], 0.f);
                    }
                }
            }
        }
    }
}

extern "C" void kernel_launch(void* const* d_in, const int* in_sizes, int n_in,
                              void* d_out, int out_size, void* d_ws, size_t ws_size,
                              hipStream_t stream) {
    const float* x     = (const float*)d_in[0];
    const float* A     = (const float*)d_in[1];
    const float* W     = (const float*)d_in[2];
    const float* gamma = (const float*)d_in[3];
    const float* beta  = (const float*)d_in[4];
    const float* mean  = (const float*)d_in[5];
    const float* var   = (const float*)d_in[6];
    float* out = (float*)d_out;

    char* ws = (char*)d_ws;
    unsigned short* wt = (unsigned short*)ws;               // 24,576 B
    unsigned short* at = (unsigned short*)(ws + 24576);     // 6,144 B

    prep_kernel<<<60, 256, 0, stream>>>(A, W, wt, at);
    mega_kernel<<<dim3(38, 32), 512, 0, stream>>>(x, wt, at, gamma, beta, mean, var, out);
}